// Round 1
// baseline (313.128 us; speedup 1.0000x reference)
//
#include <hip/hip_runtime.h>
#include <hip/hip_bf16.h>

// B=16, S=8192, D=128, H=512, N_ROT=3
// Pipeline:
//  k1:  pool partials        x (64MB) -> PART[16][64][128]
//  k2a: reduce+MLP1+gelu     PART -> pooled -> h[16][512]
//  k2b: G = h@W2^T + b2      (MFMA, W2 100MB-bound) -> GT[49152][16]  (transposed store)
//  k3:  expm per (b,rot)     s = exp(g)-I via Horner order 8, single-bf16-product + exact f32 g-add
//  k3b: compose              sR = (I+s0)(I+s1)(I+s2) - I  -> SRT bf16 stored [e][d]=sR[d][e]
//  k4:  out = x + x*sR       (MFMA, memory-bound)

typedef float  f4  __attribute__((ext_vector_type(4)));
typedef __bf16 bf8 __attribute__((ext_vector_type(8)));
typedef short  s8  __attribute__((ext_vector_type(8)));
typedef short  sh4 __attribute__((ext_vector_type(4)));

__device__ __forceinline__ short bf16s(float f) {
    unsigned u = __builtin_bit_cast(unsigned, f);
    u += 0x7FFFu + ((u >> 16) & 1u);   // RNE
    return (short)(u >> 16);
}

__device__ __forceinline__ s8 pack8(f4 lo, f4 hi) {
    s8 r;
    r[0] = bf16s(lo.x); r[1] = bf16s(lo.y); r[2] = bf16s(lo.z); r[3] = bf16s(lo.w);
    r[4] = bf16s(hi.x); r[5] = bf16s(hi.y); r[6] = bf16s(hi.z); r[7] = bf16s(hi.w);
    return r;
}

__device__ __forceinline__ f4 mfma_bf16(s8 a, s8 b, f4 c) {
    return __builtin_amdgcn_mfma_f32_16x16x32_bf16(
        __builtin_bit_cast(bf8, a), __builtin_bit_cast(bf8, b), c, 0, 0, 0);
}

// ---------------- k1: pool partial sums ----------------
// grid 16*64, block 256. Each block: one b, 128 s-rows. PART[b][chunk][128].
__global__ __launch_bounds__(256) void k1_pool(const float* __restrict__ x,
                                               float* __restrict__ part) {
    int b = blockIdx.x >> 6;
    int chunk = blockIdx.x & 63;
    int laned = (threadIdx.x & 31) * 4;   // column (float4)
    int rowg = threadIdx.x >> 5;          // 0..7
    const float* xb = x + ((size_t)b * 8192 + (size_t)chunk * 128) * 128;
    f4 acc = {0.f, 0.f, 0.f, 0.f};
    for (int r = rowg; r < 128; r += 8)
        acc += *(const f4*)(xb + (size_t)r * 128 + laned);
    __shared__ f4 red[8][32];
    red[rowg][threadIdx.x & 31] = acc;
    __syncthreads();
    if (threadIdx.x < 32) {
        f4 s = red[0][threadIdx.x];
        #pragma unroll
        for (int g = 1; g < 8; g++) s += red[g][threadIdx.x];
        *(f4*)(part + ((size_t)b * 64 + chunk) * 128 + threadIdx.x * 4) = s;
    }
}

// ---------------- k2a: reduce + MLP1 + exact gelu ----------------
// grid 16 (per b), block 512 (thread j).
__global__ __launch_bounds__(512) void k2a_h(const float* __restrict__ part,
                                             const float* __restrict__ W1,
                                             const float* __restrict__ b1,
                                             float* __restrict__ h) {
    int b = blockIdx.x;
    __shared__ float pooled[128];
    if (threadIdx.x < 128) {
        float s = 0.f;
        for (int c = 0; c < 64; c++)
            s += part[((size_t)b * 64 + c) * 128 + threadIdx.x];
        pooled[threadIdx.x] = s * (1.0f / 8192.0f);
    }
    __syncthreads();
    int j = threadIdx.x;
    const float* w = W1 + (size_t)j * 128;
    float z = b1[j];
    #pragma unroll 4
    for (int k = 0; k < 128; k += 4) {
        f4 wv = *(const f4*)(w + k);
        z += wv.x * pooled[k] + wv.y * pooled[k + 1] + wv.z * pooled[k + 2] + wv.w * pooled[k + 3];
    }
    h[(size_t)b * 512 + j] = 0.5f * z * (1.0f + erff(z * 0.70710678118654752f));
}

// ---------------- k2b: G = h @ W2^T + b2  -> GT[j][b] ----------------
// grid 768, block 256 (4 waves); wave handles one 16-wide j tile, K=512.
__global__ __launch_bounds__(256) void k2b_G(const float* __restrict__ h,
                                             const float* __restrict__ W2,
                                             const float* __restrict__ b2,
                                             float* __restrict__ GT) {
    int lane = threadIdx.x & 63;
    int wave = threadIdx.x >> 6;
    int ntile = blockIdx.x * 4 + wave;
    int cr = lane & 15, q = lane >> 4;
    int j = ntile * 16 + cr;
    const float* hA = h + (size_t)cr * 512 + 8 * q;     // A: m=b(=cr), k
    const float* wB = W2 + (size_t)j * 512 + 8 * q;     // B: n=j(=cr), k
    f4 acc = {0.f, 0.f, 0.f, 0.f};
    #pragma unroll
    for (int kc = 0; kc < 16; kc++) {
        f4 a0 = *(const f4*)(hA + kc * 32);
        f4 a1 = *(const f4*)(hA + kc * 32 + 4);
        f4 b0 = *(const f4*)(wB + kc * 32);
        f4 b1v = *(const f4*)(wB + kc * 32 + 4);
        acc = mfma_bf16(pack8(a0, a1), pack8(b0, b1v), acc);
    }
    f4 o = acc + b2[j];
    *(f4*)(GT + (size_t)j * 16 + 4 * q) = o;   // rows m = 4q+reg are b-indices
}

// ---------------- k3: s = exp(g) - I, per (b,rot) ----------------
// grid 48, block 256 (4 waves, quadrant (mh,nh) each). Horner order 8:
//   s7 = g/8 ; s_{k} = (g + g*s_{k+1})/(k+1), divisors 7..1  (7 matmuls)
// LDS: GA[r][c] = g[c][r] (f32, padded); st[n][k] = s[k][n] (bf16, padded).
// A-frag: g[m][k] = -GA[m][k]  (antisymmetry -> contiguous read + negate)
__global__ __launch_bounds__(256) void k3_expm(const float* __restrict__ GT,
                                               float* __restrict__ s_rm,
                                               float* __restrict__ s_tr) {
    __shared__ float GA[128][132];
    __shared__ short st[128][136];
    int blk = blockIdx.x;
    int bb = blk / 3, rot = blk % 3;
    const float* Gbase = GT + (size_t)rot * 16384 * 16 + bb;
    for (int idx = threadIdx.x; idx < 16384; idx += 256) {
        int r = idx >> 7, c = idx & 127;
        float Gcr = Gbase[(size_t)(c * 128 + r) * 16];   // G[b][rot][c][r]
        float Grc = Gbase[(size_t)(r * 128 + c) * 16];   // G[b][rot][r][c]
        float v = 0.5f * (Gcr - Grc);                    // g[c][r]
        GA[r][c] = v;
        st[r][c] = bf16s(v * 0.125f);                    // s7 = g/8 (st[n][k]=s[k][n])
    }
    __syncthreads();
    int lane = threadIdx.x & 63, wave = threadIdx.x >> 6;
    int mh = (wave >> 1) * 64, nh = (wave & 1) * 64;
    int cr = lane & 15, q = lane >> 4;
    s8 afr[4][4];
    #pragma unroll
    for (int mt = 0; mt < 4; mt++) {
        int m = mh + mt * 16 + cr;
        #pragma unroll
        for (int kc = 0; kc < 4; kc++) {
            int k0 = kc * 32 + 8 * q;
            f4 lo = *(const f4*)&GA[m][k0];
            f4 hi = *(const f4*)&GA[m][k0 + 4];
            afr[mt][kc] = pack8(-lo, -hi);               // g[m][k] = -GA[m][k]
        }
    }
    size_t soff = (size_t)blk * 16384;
    #pragma unroll
    for (int s = 0; s < 7; s++) {
        const float inv = 1.0f / (float)(7 - s);
        f4 acc[4][4] = {};
        #pragma unroll
        for (int nt = 0; nt < 4; nt++) {
            int n = nh + nt * 16 + cr;
            #pragma unroll
            for (int kc = 0; kc < 4; kc++) {
                s8 bfrag = *(const s8*)&st[n][kc * 32 + 8 * q];
                #pragma unroll
                for (int mt = 0; mt < 4; mt++)
                    acc[mt][nt] = mfma_bf16(afr[mt][kc], bfrag, acc[mt][nt]);
            }
        }
        __syncthreads();   // all reads of st done
        #pragma unroll
        for (int mt = 0; mt < 4; mt++) {
            int m0 = mh + mt * 16 + 4 * q;
            #pragma unroll
            for (int nt = 0; nt < 4; nt++) {
                int n = nh + nt * 16 + cr;
                f4 gv = *(const f4*)&GA[n][m0];          // g[m0..m0+3][n] (exact f32)
                f4 val = (acc[mt][nt] + gv) * inv;
                if (s < 6) {
                    sh4 w;
                    w[0] = bf16s(val.x); w[1] = bf16s(val.y);
                    w[2] = bf16s(val.z); w[3] = bf16s(val.w);
                    *(sh4*)&st[n][m0] = w;               // st[n][m] = s[m][n]
                } else {
                    *(f4*)(s_tr + soff + (size_t)n * 128 + m0) = val;
                    s_rm[soff + (size_t)(m0 + 0) * 128 + n] = val.x;
                    s_rm[soff + (size_t)(m0 + 1) * 128 + n] = val.y;
                    s_rm[soff + (size_t)(m0 + 2) * 128 + n] = val.z;
                    s_rm[soff + (size_t)(m0 + 3) * 128 + n] = val.w;
                }
            }
        }
        if (s < 6) __syncthreads();
    }
}

// ---------------- k3b: compose sR = (I+s0)(I+s1)(I+s2) - I ----------------
// grid 16, block 256 (quadrants).  T = s0+s1+s0*s1 ; sR = T+s2+T*s2.
// SRT stored bf16 as [e][d] = sR[d][e] (the k4 A-operand layout).
__global__ __launch_bounds__(256) void k3b_compose(const float* __restrict__ s_rm,
                                                   const float* __restrict__ s_tr,
                                                   float* __restrict__ sT_rm,
                                                   float* __restrict__ sT_tr,
                                                   short* __restrict__ SRT) {
    int bb = blockIdx.x;
    int lane = threadIdx.x & 63, wave = threadIdx.x >> 6;
    int mh = (wave >> 1) * 64, nh = (wave & 1) * 64;
    int cr = lane & 15, q = lane >> 4;
    const size_t o0 = (size_t)(bb * 3 + 0) * 16384;
    const size_t o1 = (size_t)(bb * 3 + 1) * 16384;
    const size_t o2 = (size_t)(bb * 3 + 2) * 16384;
    const size_t oT = (size_t)bb * 16384;

    {   // step 1
        s8 afr[4][4];
        #pragma unroll
        for (int mt = 0; mt < 4; mt++) {
            int m = mh + mt * 16 + cr;
            #pragma unroll
            for (int kc = 0; kc < 4; kc++) {
                int k0 = kc * 32 + 8 * q;
                f4 lo = *(const f4*)(s_rm + o0 + (size_t)m * 128 + k0);
                f4 hi = *(const f4*)(s_rm + o0 + (size_t)m * 128 + k0 + 4);
                afr[mt][kc] = pack8(lo, hi);
            }
        }
        f4 acc[4][4] = {};
        #pragma unroll
        for (int nt = 0; nt < 4; nt++) {
            int n = nh + nt * 16 + cr;
            #pragma unroll
            for (int kc = 0; kc < 4; kc++) {
                int k0 = kc * 32 + 8 * q;
                f4 lo = *(const f4*)(s_tr + o1 + (size_t)n * 128 + k0);
                f4 hi = *(const f4*)(s_tr + o1 + (size_t)n * 128 + k0 + 4);
                s8 bfrag = pack8(lo, hi);
                #pragma unroll
                for (int mt = 0; mt < 4; mt++)
                    acc[mt][nt] = mfma_bf16(afr[mt][kc], bfrag, acc[mt][nt]);
            }
        }
        #pragma unroll
        for (int mt = 0; mt < 4; mt++) {
            int m0 = mh + mt * 16 + 4 * q;
            #pragma unroll
            for (int nt = 0; nt < 4; nt++) {
                int n = nh + nt * 16 + cr;
                f4 a = *(const f4*)(s_tr + o0 + (size_t)n * 128 + m0);
                f4 c = *(const f4*)(s_tr + o1 + (size_t)n * 128 + m0);
                f4 val = acc[mt][nt] + a + c;
                *(f4*)(sT_tr + oT + (size_t)n * 128 + m0) = val;
                sT_rm[oT + (size_t)(m0 + 0) * 128 + n] = val.x;
                sT_rm[oT + (size_t)(m0 + 1) * 128 + n] = val.y;
                sT_rm[oT + (size_t)(m0 + 2) * 128 + n] = val.z;
                sT_rm[oT + (size_t)(m0 + 3) * 128 + n] = val.w;
            }
        }
    }
    __syncthreads();   // sT visible block-wide
    {   // step 2
        s8 afr[4][4];
        #pragma unroll
        for (int mt = 0; mt < 4; mt++) {
            int m = mh + mt * 16 + cr;
            #pragma unroll
            for (int kc = 0; kc < 4; kc++) {
                int k0 = kc * 32 + 8 * q;
                f4 lo = *(const f4*)(sT_rm + oT + (size_t)m * 128 + k0);
                f4 hi = *(const f4*)(sT_rm + oT + (size_t)m * 128 + k0 + 4);
                afr[mt][kc] = pack8(lo, hi);
            }
        }
        f4 acc[4][4] = {};
        #pragma unroll
        for (int nt = 0; nt < 4; nt++) {
            int n = nh + nt * 16 + cr;
            #pragma unroll
            for (int kc = 0; kc < 4; kc++) {
                int k0 = kc * 32 + 8 * q;
                f4 lo = *(const f4*)(s_tr + o2 + (size_t)n * 128 + k0);
                f4 hi = *(const f4*)(s_tr + o2 + (size_t)n * 128 + k0 + 4);
                s8 bfrag = pack8(lo, hi);
                #pragma unroll
                for (int mt = 0; mt < 4; mt++)
                    acc[mt][nt] = mfma_bf16(afr[mt][kc], bfrag, acc[mt][nt]);
            }
        }
        #pragma unroll
        for (int mt = 0; mt < 4; mt++) {
            int m0 = mh + mt * 16 + 4 * q;
            #pragma unroll
            for (int nt = 0; nt < 4; nt++) {
                int n = nh + nt * 16 + cr;
                f4 a = *(const f4*)(sT_tr + oT + (size_t)n * 128 + m0);
                f4 c = *(const f4*)(s_tr + o2 + (size_t)n * 128 + m0);
                f4 val = acc[mt][nt] + a + c;                 // sR[m0..+3][n]
                sh4 w;
                w[0] = bf16s(val.x); w[1] = bf16s(val.y);
                w[2] = bf16s(val.z); w[3] = bf16s(val.w);
                *(sh4*)(SRT + oT + (size_t)n * 128 + m0) = w; // SRT[e=n][d=m0..+3]
            }
        }
    }
}

// ---------------- k4: out = x + x*sR ----------------
// grid 2048 (= 16 b * 128 tiles of 64 rows), block 256 (4 waves).
// outT = sR^T * x^T + x^T : A = SRT[e][d] (preloaded frags), B = x^T from LDS bf16.
__global__ __launch_bounds__(256) void k4_apply(const float* __restrict__ x,
                                                const short* __restrict__ SRT,
                                                float* __restrict__ out) {
    __shared__ float x32[64][132];
    __shared__ short xb[64][136];
    int blk = blockIdx.x;
    int b = blk >> 7, tile = blk & 127;
    const float* xbase = x + ((size_t)b * 8192 + (size_t)tile * 64) * 128;
    float* obase = out + ((size_t)b * 8192 + (size_t)tile * 64) * 128;
    #pragma unroll
    for (int ii = 0; ii < 8; ii++) {
        int flat4 = ii * 256 + threadIdx.x;
        int row = flat4 >> 5, col = (flat4 & 31) * 4;
        f4 v = *(const f4*)(xbase + (size_t)row * 128 + col);
        *(f4*)&x32[row][col] = v;
        sh4 w;
        w[0] = bf16s(v.x); w[1] = bf16s(v.y); w[2] = bf16s(v.z); w[3] = bf16s(v.w);
        *(sh4*)&xb[row][col] = w;
    }
    int lane = threadIdx.x & 63, wave = threadIdx.x >> 6;
    int cr = lane & 15, q = lane >> 4;
    const short* Ab = SRT + (size_t)b * 16384;
    s8 afr[2][4];
    #pragma unroll
    for (int mt = 0; mt < 2; mt++) {
        int e = wave * 32 + mt * 16 + cr;
        #pragma unroll
        for (int kc = 0; kc < 4; kc++)
            afr[mt][kc] = *(const s8*)(Ab + (size_t)e * 128 + kc * 32 + 8 * q);
    }
    __syncthreads();
    #pragma unroll
    for (int strip = 0; strip < 4; strip++) {
        int srow = strip * 16 + cr;
        f4 acc0 = {0.f, 0.f, 0.f, 0.f}, acc1 = {0.f, 0.f, 0.f, 0.f};
        #pragma unroll
        for (int kc = 0; kc < 4; kc++) {
            s8 bfrag = *(const s8*)&xb[srow][kc * 32 + 8 * q];
            acc0 = mfma_bf16(afr[0][kc], bfrag, acc0);
            acc1 = mfma_bf16(afr[1][kc], bfrag, acc1);
        }
        #pragma unroll
        for (int mt = 0; mt < 2; mt++) {
            int e0 = wave * 32 + mt * 16 + 4 * q;
            f4 xv = *(const f4*)&x32[srow][e0];
            f4 o = (mt ? acc1 : acc0) + xv;
            *(f4*)(obase + (size_t)srow * 128 + e0) = o;
        }
    }
}

// ---------------- launch ----------------
extern "C" void kernel_launch(void* const* d_in, const int* in_sizes, int n_in,
                              void* d_out, int out_size, void* d_ws, size_t ws_size,
                              hipStream_t stream) {
    const float* x  = (const float*)d_in[0];
    const float* W1 = (const float*)d_in[1];
    const float* b1 = (const float*)d_in[2];
    const float* W2 = (const float*)d_in[3];
    const float* b2 = (const float*)d_in[4];
    float* out = (float*)d_out;
    float* ws = (float*)d_ws;

    float* PART  = ws;                 // 16*64*128      = 131072
    float* H     = ws + 131072;        // 16*512         = 8192
    float* GT    = ws + 139264;        // 49152*16       = 786432
    float* S_RM  = ws + 925696;        // 48*16384       = 786432
    float* S_TR  = ws + 1712128;       // 48*16384       = 786432
    float* ST_RM = ws + 2498560;       // 16*16384       = 262144
    float* ST_TR = ws + 2760704;       // 16*16384       = 262144
    short* SRT   = (short*)(ws + 3022848); // 16*16384 bf16 = 131072 floats

    hipLaunchKernelGGL(k1_pool,     dim3(1024), dim3(256), 0, stream, x, PART);
    hipLaunchKernelGGL(k2a_h,       dim3(16),   dim3(512), 0, stream, PART, W1, b1, H);
    hipLaunchKernelGGL(k2b_G,       dim3(768),  dim3(256), 0, stream, H, W2, b2, GT);
    hipLaunchKernelGGL(k3_expm,     dim3(48),   dim3(256), 0, stream, GT, S_RM, S_TR);
    hipLaunchKernelGGL(k3b_compose, dim3(16),   dim3(256), 0, stream, S_RM, S_TR, ST_RM, ST_TR, SRT);
    hipLaunchKernelGGL(k4_apply,    dim3(2048), dim3(256), 0, stream, x, SRT, out);
}